// Round 1
// baseline (171.336 us; speedup 1.0000x reference)
//
#include <hip/hip_runtime.h>
#include <hip/hip_bf16.h>

// GNNRefiner: out = xyz + max_k( relu([x_i, x_j-x_i]·W1 + b1)·W2 + b2 )
// Factorization: e·W1 = x_i·(A-B) + x_j·B  with A=W1[0:387], B=W1[387:774].
// Pipeline: prep -> knn (exact fp32) -> bf16 MFMA GEMM (U|V) -> gather/max.

#define N 8192
#define TD 384      // TOKEN_DIM
#define KNN 16
#define DX 387      // TD + 3
#define KP 416      // DX padded to multiple of 32
#define NF 768      // 2*TD output cols of fused GEMM

typedef __attribute__((ext_vector_type(8))) short short8;
typedef __attribute__((ext_vector_type(4))) float f32x4;

// ---------------- prep kernels ----------------

__global__ void prep_points(const float* __restrict__ xyz, float4* __restrict__ xyzs) {
    int i = blockIdx.x * blockDim.x + threadIdx.x;
    if (i < N) {
        float x = xyz[i*3+0], y = xyz[i*3+1], z = xyz[i*3+2];
        // match np sum order: (x*x + y*y) + z*z, no fma contraction
        float sq = __fadd_rn(__fadd_rn(__fmul_rn(x,x), __fmul_rn(y,y)), __fmul_rn(z,z));
        xyzs[i] = make_float4(x, y, z, sq);
    }
}

__global__ void prep_X(const float* __restrict__ feat, const float* __restrict__ xyz,
                       __hip_bfloat16* __restrict__ Xb) {
    int i = blockIdx.x;
    for (int d = threadIdx.x; d < KP; d += 256) {
        float v;
        if (d < TD)       v = feat[i*TD + d];
        else if (d < DX)  v = xyz[i*3 + (d - TD)];
        else              v = 0.f;
        Xb[i*KP + d] = __float2bfloat16(v);
    }
}

// Wpt[f][k] (768 x 416), bf16: f<384 -> A-B column f; f>=384 -> B column f-384
__global__ void prep_W(const float* __restrict__ W1, __hip_bfloat16* __restrict__ Wpt) {
    int f = blockIdx.x;
    for (int k = threadIdx.x; k < KP; k += 256) {
        float v = 0.f;
        if (k < DX) {
            if (f < TD) v = W1[k*TD + f] - W1[(DX+k)*TD + f];
            else        v = W1[(DX+k)*TD + (f - TD)];
        }
        Wpt[f*KP + k] = __float2bfloat16(v);
    }
}

// ---------------- knn: one wave per point, lane-distributed sorted top-16 ----------------

__global__ void __launch_bounds__(256) knn_kernel(const float4* __restrict__ xyzs,
                                                  int* __restrict__ knn) {
    __shared__ float4 pts[2048];
    const int lane = threadIdx.x & 63;
    const int wv   = threadIdx.x >> 6;
    const int i    = blockIdx.x * 4 + wv;
    const float4 me = xyzs[i];

    // sorted ascending (d2, idx): element s lives in lane s (s=0..15)
    float ld = __builtin_inff();
    int   li = -1;

    for (int chunk = 0; chunk < 4; ++chunk) {
        for (int t = threadIdx.x; t < 2048; t += 256) pts[t] = xyzs[chunk*2048 + t];
        __syncthreads();
        for (int step = 0; step < 32; ++step) {
            int j = chunk*2048 + step*64 + lane;
            float4 p = pts[step*64 + lane];
            // match reference: d2 = (sq_i + sq_j) - 2*dot, dot = fma chain
            float dot = __fmaf_rn(me.z, p.z, __fmaf_rn(me.y, p.y, __fmul_rn(me.x, p.x)));
            float d2  = __fsub_rn(__fadd_rn(me.w, p.w), __fmul_rn(2.0f, dot));
            if (j == i) d2 = __builtin_inff();

            float T = __shfl(ld, 15);
            unsigned long long mask = __ballot(d2 < T);
            while (mask) {
                int src  = __ffsll(mask) - 1;
                float cd = __shfl(d2, src);
                int   cj = __shfl(j,  src);
                // insertion position among lanes 0..15 (lexicographic (d, idx))
                bool lt = (ld < cd) || (ld == cd && li < cj);
                int pos = __popcll(__ballot(lt) & 0xFFFFull);
                float up_d = __shfl_up(ld, 1);
                int   up_i = __shfl_up(li, 1);
                if (lane > pos)       { ld = up_d; li = up_i; }
                else if (lane == pos) { ld = cd;   li = cj;  }
                T = __shfl(ld, 15);
                mask &= ~(1ull << src);
                mask &= __ballot(d2 < T);
            }
        }
        __syncthreads();
    }
    if (lane < KNN) knn[i*KNN + lane] = li;
}

// ---------------- GEMM: C[N][768] = Xb(N x 416) @ Wp(416 x 768), bf16 MFMA ----------------
// wave computes 64 rows x 16 cols; mfma_f32_16x16x32_bf16
// A-frag: lane l holds A[l&15][ (l>>4)*8 + t ]  (8 contiguous k -> 16B load)
// B-frag: lane l holds B[ (l>>4)*8 + t ][l&15]  = Wpt[f0+(l&15)][k...] (contiguous)
// C/D:    col = lane&15, row = (lane>>4)*4 + reg   [verified layout per guide]

__global__ void __launch_bounds__(256) gemm_kernel(const __hip_bfloat16* __restrict__ Xb,
                                                   const __hip_bfloat16* __restrict__ Wpt,
                                                   float* __restrict__ C) {
    const int lane = threadIdx.x & 63;
    const int wv   = threadIdx.x >> 6;
    const int i0   = blockIdx.x * 256 + wv * 64;
    const int f0   = blockIdx.y * 16;
    const int lm   = lane & 15;
    const int lk   = (lane >> 4) * 8;

    f32x4 acc[4] = {{0,0,0,0},{0,0,0,0},{0,0,0,0},{0,0,0,0}};
    const __hip_bfloat16* wrow  = Wpt + (f0 + lm) * KP + lk;
    const __hip_bfloat16* xbase = Xb  + (size_t)(i0 + lm) * KP + lk;

    #pragma unroll
    for (int kk = 0; kk < 13; ++kk) {
        short8 b = *reinterpret_cast<const short8*>(wrow + kk*32);
        #pragma unroll
        for (int r = 0; r < 4; ++r) {
            short8 a = *reinterpret_cast<const short8*>(xbase + (size_t)r*16*KP + kk*32);
            acc[r] = __builtin_amdgcn_mfma_f32_16x16x32_bf16(a, b, acc[r], 0, 0, 0);
        }
    }
    const int crow = (lane >> 4) * 4;
    #pragma unroll
    for (int r = 0; r < 4; ++r)
        #pragma unroll
        for (int q = 0; q < 4; ++q)
            C[(size_t)(i0 + r*16 + crow + q) * NF + f0 + lm] = acc[r][q];
}

// ---------------- final: out[i] = xyz[i] + b2 + max_k (relu(u_i+v_j+b1)·W2) ----------------
// one wave per point; lane owns 6 of the 384 hidden dims

__global__ void __launch_bounds__(256) final_kernel(const float* __restrict__ C,
                                                    const int* __restrict__ knn,
                                                    const float* __restrict__ xyz,
                                                    const float* __restrict__ b1,
                                                    const float* __restrict__ W2,
                                                    const float* __restrict__ b2,
                                                    float* __restrict__ out) {
    const int lane = threadIdx.x & 63;
    const int wv   = threadIdx.x >> 6;
    const int i    = blockIdx.x * 4 + wv;
    const int d0   = lane * 6;

    float u[6], w2l[6][3];
    const float* rowU = C + (size_t)i * NF;
    #pragma unroll
    for (int t = 0; t < 6; ++t) {
        u[t] = rowU[d0 + t] + b1[d0 + t];
        #pragma unroll
        for (int c = 0; c < 3; ++c) w2l[t][c] = W2[(d0 + t)*3 + c];
    }
    int jreg = knn[i*KNN + (lane & 15)];

    float mx0 = -__builtin_inff(), mx1 = -__builtin_inff(), mx2 = -__builtin_inff();
    for (int k = 0; k < KNN; ++k) {
        int j = __shfl(jreg, k);
        const float* rowV = C + (size_t)j * NF + TD;
        float s0 = 0.f, s1 = 0.f, s2 = 0.f;
        #pragma unroll
        for (int t = 0; t < 6; ++t) {
            float h = u[t] + rowV[d0 + t];
            h = fmaxf(h, 0.f);
            s0 = fmaf(h, w2l[t][0], s0);
            s1 = fmaf(h, w2l[t][1], s1);
            s2 = fmaf(h, w2l[t][2], s2);
        }
        #pragma unroll
        for (int o = 1; o < 64; o <<= 1) {
            s0 += __shfl_xor(s0, o);
            s1 += __shfl_xor(s1, o);
            s2 += __shfl_xor(s2, o);
        }
        mx0 = fmaxf(mx0, s0); mx1 = fmaxf(mx1, s1); mx2 = fmaxf(mx2, s2);
    }
    if (lane == 0) {
        out[i*3+0] = xyz[i*3+0] + mx0 + b2[0];
        out[i*3+1] = xyz[i*3+1] + mx1 + b2[1];
        out[i*3+2] = xyz[i*3+2] + mx2 + b2[2];
    }
}

// ---------------- launch ----------------

extern "C" void kernel_launch(void* const* d_in, const int* in_sizes, int n_in,
                              void* d_out, int out_size, void* d_ws, size_t ws_size,
                              hipStream_t stream) {
    const float* xyz  = (const float*)d_in[0];
    const float* feat = (const float*)d_in[1];
    const float* W1   = (const float*)d_in[2];
    const float* b1   = (const float*)d_in[3];
    const float* W2   = (const float*)d_in[4];
    const float* b2   = (const float*)d_in[5];
    float* out = (float*)d_out;

    char* ws = (char*)d_ws;
    // layout (all 16B aligned); total ~33.3 MB
    int*            knn  = (int*)(ws + 0);                  //   524288 B
    float4*         xyzs = (float4*)(ws + 524288);          //   131072 B
    __hip_bfloat16* Xb   = (__hip_bfloat16*)(ws + 655360);  //  6815744 B
    __hip_bfloat16* Wpt  = (__hip_bfloat16*)(ws + 7471104); //   638976 B
    float*          Cm   = (float*)(ws + 8110080);          // 25165824 B -> end 33275904

    prep_points<<<dim3((N + 255)/256), dim3(256), 0, stream>>>(xyz, xyzs);
    prep_X     <<<dim3(N),   dim3(256), 0, stream>>>(feat, xyz, Xb);
    prep_W     <<<dim3(NF),  dim3(256), 0, stream>>>(W1, Wpt);
    knn_kernel <<<dim3(N/4), dim3(256), 0, stream>>>(xyzs, knn);
    gemm_kernel<<<dim3(N/256, NF/16), dim3(256), 0, stream>>>(Xb, Wpt, Cm);
    final_kernel<<<dim3(N/4), dim3(256), 0, stream>>>(Cm, knn, xyz, b1, W2, b2, out);
}

// Round 2
// 130.591 us; speedup vs baseline: 1.3120x; 1.3120x over previous
//
#include <hip/hip_runtime.h>
#include <hip/hip_bf16.h>

// GNNRefiner: out = xyz + max_k( relu([x_i, x_j-x_i]·W1 + b1)·W2 + b2 )
// Factorization: e·W1 = x_i·(A-B) + x_j·B  with A=W1[0:387], B=W1[387:774].
// Pipeline: prep -> knn (exact fp32, wave-coop sorted top-16) -> bf16 MFMA GEMM -> gather/max.

#define N 8192
#define TD 384      // TOKEN_DIM
#define KNN 16
#define DX 387      // TD + 3
#define KP 416      // DX padded to multiple of 32
#define NF 768      // 2*TD output cols of fused GEMM

typedef __attribute__((ext_vector_type(8))) short short8;
typedef __attribute__((ext_vector_type(4))) float f32x4;

// ---------------- prep kernels ----------------

__global__ void prep_points(const float* __restrict__ xyz, float4* __restrict__ xyzs) {
    int i = blockIdx.x * blockDim.x + threadIdx.x;
    if (i < N) {
        float x = xyz[i*3+0], y = xyz[i*3+1], z = xyz[i*3+2];
        float sq = __fadd_rn(__fadd_rn(__fmul_rn(x,x), __fmul_rn(y,y)), __fmul_rn(z,z));
        xyzs[i] = make_float4(x, y, z, sq);
    }
}

__global__ void prep_X(const float* __restrict__ feat, const float* __restrict__ xyz,
                       __hip_bfloat16* __restrict__ Xb) {
    int i = blockIdx.x;
    for (int d = threadIdx.x; d < KP; d += 256) {
        float v;
        if (d < TD)       v = feat[i*TD + d];
        else if (d < DX)  v = xyz[i*3 + (d - TD)];
        else              v = 0.f;
        Xb[i*KP + d] = __float2bfloat16(v);
    }
}

// Wpt[f][k] (768 x 416), bf16: f<384 -> (A-B) column f; f>=384 -> B column f-384
__global__ void prep_W(const float* __restrict__ W1, __hip_bfloat16* __restrict__ Wpt) {
    int f = blockIdx.x;
    for (int k = threadIdx.x; k < KP; k += 256) {
        float v = 0.f;
        if (k < DX) {
            if (f < TD) v = W1[k*TD + f] - W1[(DX+k)*TD + f];
            else        v = W1[(DX+k)*TD + (f - TD)];
        }
        Wpt[f*KP + k] = __float2bfloat16(v);
    }
}

// ---------------- knn: one wave per point, lane-distributed sorted top-16 ----------------
// List element s lives in lane s (s=0..15), sorted ascending by (d2, idx).
// T (current 16th distance) kept in a register; readlane for uniform extracts;
// DPP row_shr:1 for the insertion shift (shfl_up by 1 within the 16-lane row).

__device__ __forceinline__ void insert16(float d2, int j, float& ld, int& li,
                                         float& T, int lane) {
    unsigned long long m = __ballot(d2 < T);
    while (m) {
        int src = (int)__ffsll((unsigned long long)m) - 1;
        float cd = __uint_as_float(__builtin_amdgcn_readlane(__float_as_uint(d2), src));
        int   cj = __builtin_amdgcn_readlane(j, src);
        bool lt = (ld < cd) || (ld == cd && li < cj);
        int pos = (int)__popcll(__ballot(lt) & 0xFFFFull);
        // shift list up by one within the 16-lane row (lane gets lane-1's value)
        float ud = __uint_as_float((unsigned)__builtin_amdgcn_update_dpp(
            (int)__float_as_uint(ld), (int)__float_as_uint(ld), 0x111, 0xF, 0xF, false));
        int   ui = __builtin_amdgcn_update_dpp(li, li, 0x111, 0xF, 0xF, false);
        ld = (lane == pos) ? cd : ((lane > pos) ? ud : ld);
        li = (lane == pos) ? cj : ((lane > pos) ? ui : li);
        T = __uint_as_float(__builtin_amdgcn_readlane(__float_as_uint(ld), 15));
        m &= ~(1ull << src);
        m &= __ballot(d2 < T);
    }
}

__global__ void __launch_bounds__(256) knn_kernel(const float4* __restrict__ xyzs,
                                                  int* __restrict__ knn) {
    const int lane = threadIdx.x & 63;
    const int wv   = threadIdx.x >> 6;
    const int i    = blockIdx.x * 4 + wv;
    const float4 me = xyzs[i];

    float ld = __builtin_inff();
    int   li = -1;
    float T  = __builtin_inff();

    for (int base = 0; base < N; base += 256) {
        const int j0 = base + lane;
        float4 p0 = xyzs[j0];
        float4 p1 = xyzs[j0 + 64];
        float4 p2 = xyzs[j0 + 128];
        float4 p3 = xyzs[j0 + 192];

        // match reference: d2 = (sq_i + sq_j) - 2*dot, dot = fma chain
        float dot0 = __fmaf_rn(me.z, p0.z, __fmaf_rn(me.y, p0.y, __fmul_rn(me.x, p0.x)));
        float dot1 = __fmaf_rn(me.z, p1.z, __fmaf_rn(me.y, p1.y, __fmul_rn(me.x, p1.x)));
        float dot2 = __fmaf_rn(me.z, p2.z, __fmaf_rn(me.y, p2.y, __fmul_rn(me.x, p2.x)));
        float dot3 = __fmaf_rn(me.z, p3.z, __fmaf_rn(me.y, p3.y, __fmul_rn(me.x, p3.x)));
        float d0 = __fsub_rn(__fadd_rn(me.w, p0.w), __fmul_rn(2.0f, dot0));
        float d1 = __fsub_rn(__fadd_rn(me.w, p1.w), __fmul_rn(2.0f, dot1));
        float d2 = __fsub_rn(__fadd_rn(me.w, p2.w), __fmul_rn(2.0f, dot2));
        float d3 = __fsub_rn(__fadd_rn(me.w, p3.w), __fmul_rn(2.0f, dot3));
        if (j0       == i) d0 = __builtin_inff();
        if (j0 + 64  == i) d1 = __builtin_inff();
        if (j0 + 128 == i) d2 = __builtin_inff();
        if (j0 + 192 == i) d3 = __builtin_inff();

        insert16(d0, j0,       ld, li, T, lane);
        insert16(d1, j0 + 64,  ld, li, T, lane);
        insert16(d2, j0 + 128, ld, li, T, lane);
        insert16(d3, j0 + 192, ld, li, T, lane);
    }
    if (lane < KNN) knn[i*KNN + lane] = li;
}

// ---------------- GEMM: Cb[N][768] = Xb(N x 416) @ Wpt^T(416 x 768), bf16 out ----------------
// wave computes 64 rows x 64 cols; mfma_f32_16x16x32_bf16
// A-frag: lane l holds A[i0 + r*16 + (l&15)][(l>>4)*8 + t]
// B-frag: lane l holds B[(l>>4)*8 + t][f0 + c*16 + (l&15)] = Wpt[f0+c*16+(l&15)][k..] contiguous
// C/D:    col = lane&15, row = (lane>>4)*4 + q   [validated round 1]

__global__ void __launch_bounds__(256) gemm_kernel(const __hip_bfloat16* __restrict__ Xb,
                                                   const __hip_bfloat16* __restrict__ Wpt,
                                                   __hip_bfloat16* __restrict__ Cb) {
    const int lane = threadIdx.x & 63;
    const int wv   = threadIdx.x >> 6;
    const int i0   = blockIdx.x * 256 + wv * 64;
    const int f0   = blockIdx.y * 64;
    const int lm   = lane & 15;
    const int lk   = (lane >> 4) * 8;

    f32x4 acc[4][4];
    #pragma unroll
    for (int r = 0; r < 4; ++r)
        #pragma unroll
        for (int c = 0; c < 4; ++c)
            acc[r][c] = (f32x4){0.f, 0.f, 0.f, 0.f};

    const __hip_bfloat16* xbase = Xb  + (size_t)(i0 + lm) * KP + lk;
    const __hip_bfloat16* wbase = Wpt + (size_t)(f0 + lm) * KP + lk;

    #pragma unroll
    for (int kk = 0; kk < 13; ++kk) {
        short8 a[4], b[4];
        #pragma unroll
        for (int r = 0; r < 4; ++r)
            a[r] = *reinterpret_cast<const short8*>(xbase + (size_t)r*16*KP + kk*32);
        #pragma unroll
        for (int c = 0; c < 4; ++c)
            b[c] = *reinterpret_cast<const short8*>(wbase + (size_t)c*16*KP + kk*32);
        #pragma unroll
        for (int r = 0; r < 4; ++r)
            #pragma unroll
            for (int c = 0; c < 4; ++c)
                acc[r][c] = __builtin_amdgcn_mfma_f32_16x16x32_bf16(a[r], b[c], acc[r][c], 0, 0, 0);
    }

    const int crow = (lane >> 4) * 4;
    #pragma unroll
    for (int r = 0; r < 4; ++r)
        #pragma unroll
        for (int c = 0; c < 4; ++c)
            #pragma unroll
            for (int q = 0; q < 4; ++q)
                Cb[(size_t)(i0 + r*16 + crow + q) * NF + f0 + c*16 + lm] =
                    __float2bfloat16(acc[r][c][q]);
}

// ---------------- final: out[i] = xyz[i] + b2 + max_k (relu(u_i+v_j+b1)·W2) ----------------
// one wave per point; lane owns 6 of the 384 hidden dims; C is bf16 (uint = 2 elems)

__device__ __forceinline__ float bflo(unsigned w) { return __uint_as_float(w << 16); }
__device__ __forceinline__ float bfhi(unsigned w) { return __uint_as_float(w & 0xFFFF0000u); }

__global__ void __launch_bounds__(256) final_kernel(const __hip_bfloat16* __restrict__ Cb,
                                                    const int* __restrict__ knn,
                                                    const float* __restrict__ xyz,
                                                    const float* __restrict__ b1,
                                                    const float* __restrict__ W2,
                                                    const float* __restrict__ b2,
                                                    float* __restrict__ out) {
    const int lane = threadIdx.x & 63;
    const int wv   = threadIdx.x >> 6;
    const int i    = blockIdx.x * 4 + wv;
    const int d0   = lane * 6;

    float u[6], w2l[6][3];
    const unsigned* rowU = reinterpret_cast<const unsigned*>(Cb + (size_t)i * NF) + lane*3;
    {
        unsigned w0 = rowU[0], w1 = rowU[1], w2 = rowU[2];
        u[0] = bflo(w0) + b1[d0+0];
        u[1] = bfhi(w0) + b1[d0+1];
        u[2] = bflo(w1) + b1[d0+2];
        u[3] = bfhi(w1) + b1[d0+3];
        u[4] = bflo(w2) + b1[d0+4];
        u[5] = bfhi(w2) + b1[d0+5];
    }
    #pragma unroll
    for (int t = 0; t < 6; ++t)
        #pragma unroll
        for (int c = 0; c < 3; ++c) w2l[t][c] = W2[(d0 + t)*3 + c];

    int jreg = knn[i*KNN + (lane & 15)];

    float mx0 = -__builtin_inff(), mx1 = -__builtin_inff(), mx2 = -__builtin_inff();
    #pragma unroll
    for (int k = 0; k < KNN; ++k) {
        int j = __shfl(jreg, k);
        const unsigned* rowV = reinterpret_cast<const unsigned*>(Cb + (size_t)j * NF + TD) + lane*3;
        unsigned w0 = rowV[0], w1 = rowV[1], w2 = rowV[2];
        float v[6];
        v[0] = bflo(w0); v[1] = bfhi(w0);
        v[2] = bflo(w1); v[3] = bfhi(w1);
        v[4] = bflo(w2); v[5] = bfhi(w2);
        float s0 = 0.f, s1 = 0.f, s2 = 0.f;
        #pragma unroll
        for (int t = 0; t < 6; ++t) {
            float h = fmaxf(u[t] + v[t], 0.f);
            s0 = fmaf(h, w2l[t][0], s0);
            s1 = fmaf(h, w2l[t][1], s1);
            s2 = fmaf(h, w2l[t][2], s2);
        }
        #pragma unroll
        for (int o = 1; o < 64; o <<= 1) {
            s0 += __shfl_xor(s0, o);
            s1 += __shfl_xor(s1, o);
            s2 += __shfl_xor(s2, o);
        }
        mx0 = fmaxf(mx0, s0); mx1 = fmaxf(mx1, s1); mx2 = fmaxf(mx2, s2);
    }
    if (lane == 0) {
        out[i*3+0] = xyz[i*3+0] + mx0 + b2[0];
        out[i*3+1] = xyz[i*3+1] + mx1 + b2[1];
        out[i*3+2] = xyz[i*3+2] + mx2 + b2[2];
    }
}

// ---------------- launch ----------------

extern "C" void kernel_launch(void* const* d_in, const int* in_sizes, int n_in,
                              void* d_out, int out_size, void* d_ws, size_t ws_size,
                              hipStream_t stream) {
    const float* xyz  = (const float*)d_in[0];
    const float* feat = (const float*)d_in[1];
    const float* W1   = (const float*)d_in[2];
    const float* b1   = (const float*)d_in[3];
    const float* W2   = (const float*)d_in[4];
    const float* b2   = (const float*)d_in[5];
    float* out = (float*)d_out;

    char* ws = (char*)d_ws;
    // layout (16B aligned); total ~20.7 MB
    int*            knn  = (int*)(ws + 0);                  //   524288 B
    float4*         xyzs = (float4*)(ws + 524288);          //   131072 B
    __hip_bfloat16* Xb   = (__hip_bfloat16*)(ws + 655360);  //  6815744 B
    __hip_bfloat16* Wpt  = (__hip_bfloat16*)(ws + 7471104); //   638976 B
    __hip_bfloat16* Cb   = (__hip_bfloat16*)(ws + 8110080); // 12582912 B -> end 20692992

    prep_points<<<dim3((N + 255)/256), dim3(256), 0, stream>>>(xyz, xyzs);
    prep_X     <<<dim3(N),   dim3(256), 0, stream>>>(feat, xyz, Xb);
    prep_W     <<<dim3(NF),  dim3(256), 0, stream>>>(W1, Wpt);
    knn_kernel <<<dim3(N/4), dim3(256), 0, stream>>>(xyzs, knn);
    gemm_kernel<<<dim3(N/256, NF/64), dim3(256), 0, stream>>>(Xb, Wpt, Cb);
    final_kernel<<<dim3(N/4), dim3(256), 0, stream>>>(Cb, knn, xyz, b1, W2, b2, out);
}

// Round 3
// 119.160 us; speedup vs baseline: 1.4379x; 1.0959x over previous
//
#include <hip/hip_runtime.h>
#include <hip/hip_bf16.h>

// GNNRefiner: out = xyz + max_k( relu([x_i, x_j-x_i]·W1 + b1)·W2 + b2 )
// Factorization: e·W1 = x_i·(A-B) + x_j·B  with A=W1[0:387], B=W1[387:774].
// Pipeline: prep(fused) -> knn (exact fp32, packed-f32 scan) -> bf16 MFMA GEMM -> gather/max.

#define N 8192
#define NTILES 32   // N/256
#define TD 384      // TOKEN_DIM
#define KNN 16
#define DX 387      // TD + 3
#define KP 416      // DX padded to multiple of 32
#define NF 768      // 2*TD output cols of fused GEMM

typedef __attribute__((ext_vector_type(8))) short short8;
typedef __attribute__((ext_vector_type(4))) float f32x4;
typedef __attribute__((ext_vector_type(2))) float f32x2;

// ---------------- packed fp32 helpers (bit-identical to scalar ops, 2 lanes/instr) ----------------

__device__ __forceinline__ f32x2 pk_mul(f32x2 a, f32x2 b) {
    f32x2 r; asm("v_pk_mul_f32 %0, %1, %2" : "=v"(r) : "v"(a), "v"(b)); return r;
}
__device__ __forceinline__ f32x2 pk_add(f32x2 a, f32x2 b) {
    f32x2 r; asm("v_pk_add_f32 %0, %1, %2" : "=v"(r) : "v"(a), "v"(b)); return r;
}
__device__ __forceinline__ f32x2 pk_sub(f32x2 a, f32x2 b) {  // a - b, same rounding as fsub
    f32x2 r; asm("v_pk_add_f32 %0, %1, %2 neg_lo:[0,1] neg_hi:[0,1]" : "=v"(r) : "v"(a), "v"(b)); return r;
}
__device__ __forceinline__ f32x2 pk_fma(f32x2 a, f32x2 b, f32x2 c) {
    f32x2 r; asm("v_pk_fma_f32 %0, %1, %2, %3" : "=v"(r) : "v"(a), "v"(b), "v"(c)); return r;
}

// ---------------- fused prep: Xb rows + point tiles + Wpt ----------------
// tiles: per 256-pt tile: [x(256) | y(256) | z(256) | sq(256)] floats (4KB)

__global__ void prep_all(const float* __restrict__ feat, const float* __restrict__ xyz,
                         const float* __restrict__ W1,
                         float* __restrict__ tiles, __hip_bfloat16* __restrict__ Xb,
                         __hip_bfloat16* __restrict__ Wpt) {
    int b = blockIdx.x;
    if (b < N) {
        int d = threadIdx.x;                 // 0..255, all < TD
        Xb[b*KP + d] = __float2bfloat16(feat[b*TD + d]);
        int d2 = 256 + threadIdx.x;
        if (d2 < KP) {
            float v;
            if (d2 < TD)      v = feat[b*TD + d2];
            else if (d2 < DX) v = xyz[b*3 + (d2 - TD)];
            else              v = 0.f;
            Xb[b*KP + d2] = __float2bfloat16(v);
        }
        if (threadIdx.x == 0) {
            float x = xyz[b*3+0], y = xyz[b*3+1], z = xyz[b*3+2];
            float sq = __fadd_rn(__fadd_rn(__fmul_rn(x,x), __fmul_rn(y,y)), __fmul_rn(z,z));
            float* tp = tiles + (b >> 8) * 1024 + (b & 255);
            tp[0] = x; tp[256] = y; tp[512] = z; tp[768] = sq;
        }
    } else {
        int f = b - N;  // 0..767
        for (int k = threadIdx.x; k < KP; k += 256) {
            float v = 0.f;
            if (k < DX) {
                if (f < TD) v = W1[k*TD + f] - W1[(DX+k)*TD + f];
                else        v = W1[(DX+k)*TD + (f - TD)];
            }
            Wpt[f*KP + k] = __float2bfloat16(v);
        }
    }
}

// ---------------- knn: one wave per point, lane-distributed sorted top-16 ----------------
// List element s lives in lane s (s=0..15), sorted ascending by (d2, idx).
// Lane handles 4 ADJACENT candidates j = tile*256 + lane*4 + s.

__device__ __forceinline__ float dpp_shr1_f(float v) {
    return __uint_as_float((unsigned)__builtin_amdgcn_update_dpp(
        (int)__float_as_uint(v), (int)__float_as_uint(v), 0x111, 0xF, 0xF, false));
}
__device__ __forceinline__ int dpp_shr1_i(int v) {
    return __builtin_amdgcn_update_dpp(v, v, 0x111, 0xF, 0xF, false);
}

__device__ __forceinline__ void insert1(float dv, int jbase, int s,
                                        float& ld, int& li, float& T, int lane) {
    unsigned long long m = __ballot(dv < T);
    while (m) {
        int src = (int)__ffsll(m) - 1;
        float cd = __uint_as_float(__builtin_amdgcn_readlane(__float_as_uint(dv), src));
        int   cj = jbase + src*4 + s;   // scalar
        bool lt = (ld < cd) || (ld == cd && li < cj);
        int pos = (int)__popcll(__ballot(lt) & 0xFFFFull);
        float ud = dpp_shr1_f(ld);
        int   ui = dpp_shr1_i(li);
        ld = (lane == pos) ? cd : ((lane > pos) ? ud : ld);
        li = (lane == pos) ? cj : ((lane > pos) ? ui : li);
        T = __uint_as_float(__builtin_amdgcn_readlane(__float_as_uint(ld), 15));
        m &= ~(1ull << src);
        m &= __ballot(dv < T);
    }
}

__global__ void __launch_bounds__(256) knn_kernel(const float* __restrict__ tiles,
                                                  int* __restrict__ knn) {
    const int lane = threadIdx.x & 63;
    const int wv   = threadIdx.x >> 6;
    const int i    = blockIdx.x * 4 + wv;

    const float* mp = tiles + (i >> 8) * 1024 + (i & 255);
    const float mex = mp[0], mey = mp[256], mez = mp[512], mew = mp[768];
    const f32x2 mx2 = {mex, mex}, my2 = {mey, mey}, mz2 = {mez, mez}, mw2 = {mew, mew};

    float ld = __builtin_inff();
    int   li = -1;
    float T  = __builtin_inff();

    const int self_tile = i >> 8;
    const int self_lane = (i & 255) >> 2;
    const int self_slot = i & 3;

    for (int t = 0; t < NTILES; ++t) {
        const float* tp = tiles + t*1024 + lane*4;
        float4 X = *reinterpret_cast<const float4*>(tp);
        float4 Y = *reinterpret_cast<const float4*>(tp + 256);
        float4 Z = *reinterpret_cast<const float4*>(tp + 512);
        float4 S = *reinterpret_cast<const float4*>(tp + 768);

        // d2 = (me.w + sq_j) - 2*dot, dot = fma(mz,z, fma(my,y, mul(mx,x)))  [bit-identical]
        f32x2 x01 = {X.x, X.y}, x23 = {X.z, X.w};
        f32x2 y01 = {Y.x, Y.y}, y23 = {Y.z, Y.w};
        f32x2 z01 = {Z.x, Z.y}, z23 = {Z.z, Z.w};
        f32x2 s01 = {S.x, S.y}, s23 = {S.z, S.w};

        f32x2 dot01 = pk_fma(mz2, z01, pk_fma(my2, y01, pk_mul(mx2, x01)));
        f32x2 dot23 = pk_fma(mz2, z23, pk_fma(my2, y23, pk_mul(mx2, x23)));
        f32x2 d01 = pk_sub(pk_add(mw2, s01), pk_add(dot01, dot01));  // dot+dot == 2*dot exactly
        f32x2 d23 = pk_sub(pk_add(mw2, s23), pk_add(dot23, dot23));

        float d[4] = {d01[0], d01[1], d23[0], d23[1]};
        if (t == self_tile) {
            #pragma unroll
            for (int s = 0; s < 4; ++s)
                if (s == self_slot) d[s] = (lane == self_lane) ? __builtin_inff() : d[s];
        }
        const int jbase = t * 256;
        insert1(d[0], jbase, 0, ld, li, T, lane);
        insert1(d[1], jbase, 1, ld, li, T, lane);
        insert1(d[2], jbase, 2, ld, li, T, lane);
        insert1(d[3], jbase, 3, ld, li, T, lane);
    }
    if (lane < KNN) knn[i*KNN + lane] = li;
}

// ---------------- GEMM: Cb[N][768] = Xb(N x 416) @ Wpt^T, bf16 out ----------------
// 1 wave per block, 64 rows x 64 cols; mfma_f32_16x16x32_bf16
// C/D: col = lane&15, row = (lane>>4)*4 + q

__global__ void __launch_bounds__(64) gemm_kernel(const __hip_bfloat16* __restrict__ Xb,
                                                  const __hip_bfloat16* __restrict__ Wpt,
                                                  __hip_bfloat16* __restrict__ Cb) {
    const int lane = threadIdx.x;
    const int i0   = blockIdx.x * 64;
    const int f0   = blockIdx.y * 64;
    const int lm   = lane & 15;
    const int lk   = (lane >> 4) * 8;

    f32x4 acc[4][4];
    #pragma unroll
    for (int r = 0; r < 4; ++r)
        #pragma unroll
        for (int c = 0; c < 4; ++c)
            acc[r][c] = (f32x4){0.f, 0.f, 0.f, 0.f};

    const __hip_bfloat16* xbase = Xb  + (size_t)(i0 + lm) * KP + lk;
    const __hip_bfloat16* wbase = Wpt + (size_t)(f0 + lm) * KP + lk;

    #pragma unroll
    for (int kk = 0; kk < 13; ++kk) {
        short8 a[4], b[4];
        #pragma unroll
        for (int r = 0; r < 4; ++r)
            a[r] = *reinterpret_cast<const short8*>(xbase + (size_t)r*16*KP + kk*32);
        #pragma unroll
        for (int c = 0; c < 4; ++c)
            b[c] = *reinterpret_cast<const short8*>(wbase + (size_t)c*16*KP + kk*32);
        #pragma unroll
        for (int r = 0; r < 4; ++r)
            #pragma unroll
            for (int c = 0; c < 4; ++c)
                acc[r][c] = __builtin_amdgcn_mfma_f32_16x16x32_bf16(a[r], b[c], acc[r][c], 0, 0, 0);
    }

    const int crow = (lane >> 4) * 4;
    #pragma unroll
    for (int r = 0; r < 4; ++r)
        #pragma unroll
        for (int c = 0; c < 4; ++c)
            #pragma unroll
            for (int q = 0; q < 4; ++q)
                Cb[(size_t)(i0 + r*16 + crow + q) * NF + f0 + c*16 + lm] =
                    __float2bfloat16(acc[r][c][q]);
}

// ---------------- final: out[i] = xyz[i] + b2 + max_k (relu(u_i+v_j+b1)·W2) ----------------

__device__ __forceinline__ float bflo(unsigned w) { return __uint_as_float(w << 16); }
__device__ __forceinline__ float bfhi(unsigned w) { return __uint_as_float(w & 0xFFFF0000u); }

__global__ void __launch_bounds__(256) final_kernel(const __hip_bfloat16* __restrict__ Cb,
                                                    const int* __restrict__ knn,
                                                    const float* __restrict__ xyz,
                                                    const float* __restrict__ b1,
                                                    const float* __restrict__ W2,
                                                    const float* __restrict__ b2,
                                                    float* __restrict__ out) {
    const int lane = threadIdx.x & 63;
    const int wv   = threadIdx.x >> 6;
    const int i    = blockIdx.x * 4 + wv;
    const int d0   = lane * 6;

    float u[6], w2l[6][3];
    const unsigned* rowU = reinterpret_cast<const unsigned*>(Cb + (size_t)i * NF) + lane*3;
    {
        unsigned w0 = rowU[0], w1 = rowU[1], w2 = rowU[2];
        u[0] = bflo(w0) + b1[d0+0];
        u[1] = bfhi(w0) + b1[d0+1];
        u[2] = bflo(w1) + b1[d0+2];
        u[3] = bfhi(w1) + b1[d0+3];
        u[4] = bflo(w2) + b1[d0+4];
        u[5] = bfhi(w2) + b1[d0+5];
    }
    #pragma unroll
    for (int t = 0; t < 6; ++t)
        #pragma unroll
        for (int c = 0; c < 3; ++c) w2l[t][c] = W2[(d0 + t)*3 + c];

    int jreg = knn[i*KNN + (lane & 15)];

    float mx0 = -__builtin_inff(), mx1 = -__builtin_inff(), mx2 = -__builtin_inff();
    #pragma unroll
    for (int k = 0; k < KNN; ++k) {
        int j = __shfl(jreg, k);
        const unsigned* rowV = reinterpret_cast<const unsigned*>(Cb + (size_t)j * NF + TD) + lane*3;
        unsigned w0 = rowV[0], w1 = rowV[1], w2 = rowV[2];
        float v[6];
        v[0] = bflo(w0); v[1] = bfhi(w0);
        v[2] = bflo(w1); v[3] = bfhi(w1);
        v[4] = bflo(w2); v[5] = bfhi(w2);
        float s0 = 0.f, s1 = 0.f, s2 = 0.f;
        #pragma unroll
        for (int t = 0; t < 6; ++t) {
            float h = fmaxf(u[t] + v[t], 0.f);
            s0 = fmaf(h, w2l[t][0], s0);
            s1 = fmaf(h, w2l[t][1], s1);
            s2 = fmaf(h, w2l[t][2], s2);
        }
        #pragma unroll
        for (int o = 1; o < 64; o <<= 1) {
            s0 += __shfl_xor(s0, o);
            s1 += __shfl_xor(s1, o);
            s2 += __shfl_xor(s2, o);
        }
        mx0 = fmaxf(mx0, s0); mx1 = fmaxf(mx1, s1); mx2 = fmaxf(mx2, s2);
    }
    if (lane == 0) {
        out[i*3+0] = xyz[i*3+0] + mx0 + b2[0];
        out[i*3+1] = xyz[i*3+1] + mx1 + b2[1];
        out[i*3+2] = xyz[i*3+2] + mx2 + b2[2];
    }
}

// ---------------- launch ----------------

extern "C" void kernel_launch(void* const* d_in, const int* in_sizes, int n_in,
                              void* d_out, int out_size, void* d_ws, size_t ws_size,
                              hipStream_t stream) {
    const float* xyz  = (const float*)d_in[0];
    const float* feat = (const float*)d_in[1];
    const float* W1   = (const float*)d_in[2];
    const float* b1   = (const float*)d_in[3];
    const float* W2   = (const float*)d_in[4];
    const float* b2   = (const float*)d_in[5];
    float* out = (float*)d_out;

    char* ws = (char*)d_ws;
    int*            knn   = (int*)(ws + 0);                  //   524288 B
    float*          tiles = (float*)(ws + 524288);           //   131072 B
    __hip_bfloat16* Xb    = (__hip_bfloat16*)(ws + 655360);  //  6815744 B
    __hip_bfloat16* Wpt   = (__hip_bfloat16*)(ws + 7471104); //   638976 B
    __hip_bfloat16* Cb    = (__hip_bfloat16*)(ws + 8110080); // 12582912 B -> end 20692992

    prep_all   <<<dim3(N + NF),        dim3(256), 0, stream>>>(feat, xyz, W1, tiles, Xb, Wpt);
    knn_kernel <<<dim3(N/4),           dim3(256), 0, stream>>>(tiles, knn);
    gemm_kernel<<<dim3(N/64, NF/64),   dim3(64),  0, stream>>>(Xb, Wpt, Cb);
    final_kernel<<<dim3(N/4),          dim3(256), 0, stream>>>(Cb, knn, xyz, b1, W2, b2, out);
}

// Round 4
// 118.233 us; speedup vs baseline: 1.4491x; 1.0078x over previous
//
#include <hip/hip_runtime.h>
#include <hip/hip_bf16.h>

// GNNRefiner: out = xyz + max_k( relu([x_i, x_j-x_i]·W1 + b1)·W2 + b2 )
// Factorization: e·W1 = x_i·(A-B) + x_j·B  with A=W1[0:387], B=W1[387:774].
// Pipeline: prep(fused) -> knn (two-pass exact fp32) -> bf16 MFMA GEMM -> gather/max.
// KNN: pass1 computes per-lane minima -> T = 16th smallest lane-min (valid upper
// bound on the true 16th distance); pass2 re-derives bit-identical distances and
// only runs the serial sorted-insert for candidates with d <= T (~20 vs ~116).

#define N 8192
#define NTILES 32   // N/256
#define TD 384      // TOKEN_DIM
#define KNN 16
#define DX 387      // TD + 3
#define KP 416      // DX padded to multiple of 32
#define NF 768      // 2*TD output cols of fused GEMM
#define INFF __builtin_inff()

typedef __attribute__((ext_vector_type(8))) short short8;
typedef __attribute__((ext_vector_type(4))) float f32x4;
typedef __attribute__((ext_vector_type(2))) float f32x2;

// ---------------- packed fp32 helpers (bit-identical to scalar ops, 2 cands/instr) ----------------

__device__ __forceinline__ f32x2 pk_mul(f32x2 a, f32x2 b) {
    f32x2 r; asm("v_pk_mul_f32 %0, %1, %2" : "=v"(r) : "v"(a), "v"(b)); return r;
}
__device__ __forceinline__ f32x2 pk_add(f32x2 a, f32x2 b) {
    f32x2 r; asm("v_pk_add_f32 %0, %1, %2" : "=v"(r) : "v"(a), "v"(b)); return r;
}
__device__ __forceinline__ f32x2 pk_sub(f32x2 a, f32x2 b) {  // a - b, same rounding as fsub
    f32x2 r; asm("v_pk_add_f32 %0, %1, %2 neg_lo:[0,1] neg_hi:[0,1]" : "=v"(r) : "v"(a), "v"(b)); return r;
}
__device__ __forceinline__ f32x2 pk_fma(f32x2 a, f32x2 b, f32x2 c) {
    f32x2 r; asm("v_pk_fma_f32 %0, %1, %2, %3" : "=v"(r) : "v"(a), "v"(b), "v"(c)); return r;
}

// d2 = (qw + sq_j) - 2*dot, dot = fma(qz,z, fma(qy,y, mul(qx,x)))  [bit-identical to ref]
__device__ __forceinline__ void dist4(f32x2 qx, f32x2 qy, f32x2 qz, f32x2 qw,
                                      f32x2 x01, f32x2 x23, f32x2 y01, f32x2 y23,
                                      f32x2 z01, f32x2 z23, f32x2 s01, f32x2 s23,
                                      f32x2& d01, f32x2& d23) {
    f32x2 dot01 = pk_fma(qz, z01, pk_fma(qy, y01, pk_mul(qx, x01)));
    f32x2 dot23 = pk_fma(qz, z23, pk_fma(qy, y23, pk_mul(qx, x23)));
    d01 = pk_sub(pk_add(qw, s01), pk_add(dot01, dot01));  // dot+dot == 2*dot exactly
    d23 = pk_sub(pk_add(qw, s23), pk_add(dot23, dot23));
}

// ---------------- fused prep: Xb rows + point tiles + Wpt ----------------
// tiles: per 256-pt tile: [x(256) | y(256) | z(256) | sq(256)] floats (4KB)

__global__ void prep_all(const float* __restrict__ feat, const float* __restrict__ xyz,
                         const float* __restrict__ W1,
                         float* __restrict__ tiles, __hip_bfloat16* __restrict__ Xb,
                         __hip_bfloat16* __restrict__ Wpt) {
    int b = blockIdx.x;
    if (b < N) {
        int d = threadIdx.x;                 // 0..255, all < TD
        Xb[b*KP + d] = __float2bfloat16(feat[b*TD + d]);
        int d2 = 256 + threadIdx.x;
        if (d2 < KP) {
            float v;
            if (d2 < TD)      v = feat[b*TD + d2];
            else if (d2 < DX) v = xyz[b*3 + (d2 - TD)];
            else              v = 0.f;
            Xb[b*KP + d2] = __float2bfloat16(v);
        }
        if (threadIdx.x == 0) {
            float x = xyz[b*3+0], y = xyz[b*3+1], z = xyz[b*3+2];
            float sq = __fadd_rn(__fadd_rn(__fmul_rn(x,x), __fmul_rn(y,y)), __fmul_rn(z,z));
            float* tp = tiles + (b >> 8) * 1024 + (b & 255);
            tp[0] = x; tp[256] = y; tp[512] = z; tp[768] = sq;
        }
    } else {
        int f = b - N;  // 0..767
        for (int k = threadIdx.x; k < KP; k += 256) {
            float v = 0.f;
            if (k < DX) {
                if (f < TD) v = W1[k*TD + f] - W1[(DX+k)*TD + f];
                else        v = W1[(DX+k)*TD + (f - TD)];
            }
            Wpt[f*KP + k] = __float2bfloat16(v);
        }
    }
}

// ---------------- knn helpers ----------------

__device__ __forceinline__ float dpp_shr1_f(float v) {
    return __uint_as_float((unsigned)__builtin_amdgcn_update_dpp(
        (int)__float_as_uint(v), (int)__float_as_uint(v), 0x111, 0xF, 0xF, false));
}
__device__ __forceinline__ int dpp_shr1_i(int v) {
    return __builtin_amdgcn_update_dpp(v, v, 0x111, 0xF, 0xF, false);
}
__device__ __forceinline__ float rdlane_f(float v, int src) {
    return __uint_as_float(__builtin_amdgcn_readlane(__float_as_uint(v), src));
}

// Sorted-by-lane top-16 insert: list element s in lane s (s=0..15), ascending (d2, idx).
// Tq pre-mask keeps the accept count ~= |{d <= Tq}| instead of ~16*ln(n/16).
__device__ __forceinline__ void insert16(float dv, int jbase, float Tq,
                                         float& ld, int& li, float& Tl, int lane) {
    unsigned long long m = __ballot((dv <= Tq) && (dv < Tl));
    while (m) {
        int src = (int)__ffsll(m) - 1;
        float cd = rdlane_f(dv, src);
        int   cj = jbase + src*4;      // scalar: candidate index
        bool lt = (ld < cd) || (ld == cd && li < cj);
        int pos = (int)__popcll(__ballot(lt) & 0xFFFFull);
        float ud = dpp_shr1_f(ld);
        int   ui = dpp_shr1_i(li);
        ld = (lane == pos) ? cd : ((lane > pos) ? ud : ld);
        li = (lane == pos) ? cj : ((lane > pos) ? ui : li);
        Tl = rdlane_f(ld, 15);
        m &= ~(1ull << src);
        m &= __ballot(dv < Tl);
    }
}

// ---------------- knn: one wave per 4 queries, two-pass ----------------

__global__ void __launch_bounds__(256) knn_kernel(const float* __restrict__ tiles,
                                                  int* __restrict__ knn) {
    const int lane = threadIdx.x & 63;
    const int wv   = threadIdx.x >> 6;
    const int i0   = (blockIdx.x * 4 + wv) * 4;   // 4 consecutive queries
    const int st   = i0 >> 8;                     // self tile (shared by all 4)
    const int sl   = (i0 & 255) >> 2;             // self lane; query q -> slot q

    // query coords (4 consecutive points, same tile)
    const float* qp = tiles + st * 1024 + (i0 & 255);
    f32x4 QX = *(const f32x4*)(qp);
    f32x4 QY = *(const f32x4*)(qp + 256);
    f32x4 QZ = *(const f32x4*)(qp + 512);
    f32x4 QW = *(const f32x4*)(qp + 768);
    f32x2 qx2[4], qy2[4], qz2[4], qw2[4];
    #pragma unroll
    for (int q = 0; q < 4; ++q) {
        qx2[q] = (f32x2){QX[q], QX[q]};
        qy2[q] = (f32x2){QY[q], QY[q]};
        qz2[q] = (f32x2){QZ[q], QZ[q]};
        qw2[q] = (f32x2){QW[q], QW[q]};
    }

    // ---- pass 1: per-lane minima ----
    float mn[4] = {INFF, INFF, INFF, INFF};
    for (int t = 0; t < NTILES; ++t) {
        const float* tp = tiles + t*1024 + lane*4;
        f32x4 X = *(const f32x4*)(tp);
        f32x4 Y = *(const f32x4*)(tp + 256);
        f32x4 Z = *(const f32x4*)(tp + 512);
        f32x4 S = *(const f32x4*)(tp + 768);
        f32x2 x01 = {X[0],X[1]}, x23 = {X[2],X[3]};
        f32x2 y01 = {Y[0],Y[1]}, y23 = {Y[2],Y[3]};
        f32x2 z01 = {Z[0],Z[1]}, z23 = {Z[2],Z[3]};
        f32x2 s01 = {S[0],S[1]}, s23 = {S[2],S[3]};
        const bool selft = (t == st) && (lane == sl);
        #pragma unroll
        for (int q = 0; q < 4; ++q) {
            f32x2 d01, d23;
            dist4(qx2[q], qy2[q], qz2[q], qw2[q],
                  x01, x23, y01, y23, z01, z23, s01, s23, d01, d23);
            if (selft) {
                if      (q == 0) d01[0] = INFF;
                else if (q == 1) d01[1] = INFF;
                else if (q == 2) d23[0] = INFF;
                else             d23[1] = INFF;
            }
            mn[q] = fminf(mn[q], fminf(fminf(d01[0], d01[1]), fminf(d23[0], d23[1])));
        }
    }

    // ---- T[q] = exact 16th smallest of the 64 lane minima (bitonic sort) ----
    float v0 = mn[0], v1 = mn[1], v2 = mn[2], v3 = mn[3];
    #pragma unroll
    for (int k = 2; k <= 64; k <<= 1) {
        #pragma unroll
        for (int j = k >> 1; j >= 1; j >>= 1) {
            const bool keepmin = ((lane & k) == 0) == ((lane & j) == 0);
            float o0 = __shfl_xor(v0, j), o1 = __shfl_xor(v1, j);
            float o2 = __shfl_xor(v2, j), o3 = __shfl_xor(v3, j);
            v0 = keepmin ? fminf(v0, o0) : fmaxf(v0, o0);
            v1 = keepmin ? fminf(v1, o1) : fmaxf(v1, o1);
            v2 = keepmin ? fminf(v2, o2) : fmaxf(v2, o2);
            v3 = keepmin ? fminf(v3, o3) : fmaxf(v3, o3);
        }
    }
    float T[4];
    T[0] = rdlane_f(v0, 15); T[1] = rdlane_f(v1, 15);
    T[2] = rdlane_f(v2, 15); T[3] = rdlane_f(v3, 15);

    // ---- pass 2: exact top-16 over prefiltered candidates ----
    float ld[4] = {INFF, INFF, INFF, INFF};
    int   li[4] = {-1, -1, -1, -1};
    float Tl[4] = {INFF, INFF, INFF, INFF};

    for (int t = 0; t < NTILES; ++t) {
        const float* tp = tiles + t*1024 + lane*4;
        f32x4 X = *(const f32x4*)(tp);
        f32x4 Y = *(const f32x4*)(tp + 256);
        f32x4 Z = *(const f32x4*)(tp + 512);
        f32x4 S = *(const f32x4*)(tp + 768);
        f32x2 x01 = {X[0],X[1]}, x23 = {X[2],X[3]};
        f32x2 y01 = {Y[0],Y[1]}, y23 = {Y[2],Y[3]};
        f32x2 z01 = {Z[0],Z[1]}, z23 = {Z[2],Z[3]};
        f32x2 s01 = {S[0],S[1]}, s23 = {S[2],S[3]};
        const bool selft = (t == st) && (lane == sl);
        #pragma unroll
        for (int q = 0; q < 4; ++q) {
            f32x2 d01, d23;
            dist4(qx2[q], qy2[q], qz2[q], qw2[q],
                  x01, x23, y01, y23, z01, z23, s01, s23, d01, d23);
            if (selft) {
                if      (q == 0) d01[0] = INFF;
                else if (q == 1) d01[1] = INFF;
                else if (q == 2) d23[0] = INFF;
                else             d23[1] = INFF;
            }
            float tmin = fminf(fminf(d01[0], d01[1]), fminf(d23[0], d23[1]));
            if (__ballot(tmin <= T[q])) {
                insert16(d01[0], t*256 + 0, T[q], ld[q], li[q], Tl[q], lane);
                insert16(d01[1], t*256 + 1, T[q], ld[q], li[q], Tl[q], lane);
                insert16(d23[0], t*256 + 2, T[q], ld[q], li[q], Tl[q], lane);
                insert16(d23[1], t*256 + 3, T[q], ld[q], li[q], Tl[q], lane);
            }
        }
    }
    if (lane < KNN) {
        #pragma unroll
        for (int q = 0; q < 4; ++q)
            knn[(i0 + q)*KNN + lane] = li[q];
    }
}

// ---------------- GEMM: Cb[N][768] = Xb(N x 416) @ Wpt^T, bf16 out ----------------
// 1 wave per block, 64 rows x 64 cols; mfma_f32_16x16x32_bf16
// C/D: col = lane&15, row = (lane>>4)*4 + q

__global__ void __launch_bounds__(64) gemm_kernel(const __hip_bfloat16* __restrict__ Xb,
                                                  const __hip_bfloat16* __restrict__ Wpt,
                                                  __hip_bfloat16* __restrict__ Cb) {
    const int lane = threadIdx.x;
    const int i0   = blockIdx.x * 64;
    const int f0   = blockIdx.y * 64;
    const int lm   = lane & 15;
    const int lk   = (lane >> 4) * 8;

    f32x4 acc[4][4];
    #pragma unroll
    for (int r = 0; r < 4; ++r)
        #pragma unroll
        for (int c = 0; c < 4; ++c)
            acc[r][c] = (f32x4){0.f, 0.f, 0.f, 0.f};

    const __hip_bfloat16* xbase = Xb  + (size_t)(i0 + lm) * KP + lk;
    const __hip_bfloat16* wbase = Wpt + (size_t)(f0 + lm) * KP + lk;

    #pragma unroll
    for (int kk = 0; kk < 13; ++kk) {
        short8 a[4], b[4];
        #pragma unroll
        for (int r = 0; r < 4; ++r)
            a[r] = *reinterpret_cast<const short8*>(xbase + (size_t)r*16*KP + kk*32);
        #pragma unroll
        for (int c = 0; c < 4; ++c)
            b[c] = *reinterpret_cast<const short8*>(wbase + (size_t)c*16*KP + kk*32);
        #pragma unroll
        for (int r = 0; r < 4; ++r)
            #pragma unroll
            for (int c = 0; c < 4; ++c)
                acc[r][c] = __builtin_amdgcn_mfma_f32_16x16x32_bf16(a[r], b[c], acc[r][c], 0, 0, 0);
    }

    const int crow = (lane >> 4) * 4;
    #pragma unroll
    for (int r = 0; r < 4; ++r)
        #pragma unroll
        for (int c = 0; c < 4; ++c)
            #pragma unroll
            for (int q = 0; q < 4; ++q)
                Cb[(size_t)(i0 + r*16 + crow + q) * NF + f0 + c*16 + lm] =
                    __float2bfloat16(acc[r][c][q]);
}

// ---------------- final: out[i] = xyz[i] + b2 + max_k (relu(u_i+v_j+b1)·W2) ----------------

__device__ __forceinline__ float bflo(unsigned w) { return __uint_as_float(w << 16); }
__device__ __forceinline__ float bfhi(unsigned w) { return __uint_as_float(w & 0xFFFF0000u); }

__global__ void __launch_bounds__(256) final_kernel(const __hip_bfloat16* __restrict__ Cb,
                                                    const int* __restrict__ knn,
                                                    const float* __restrict__ xyz,
                                                    const float* __restrict__ b1,
                                                    const float* __restrict__ W2,
                                                    const float* __restrict__ b2,
                                                    float* __restrict__ out) {
    const int lane = threadIdx.x & 63;
    const int wv   = threadIdx.x >> 6;
    const int i    = blockIdx.x * 4 + wv;
    const int d0   = lane * 6;

    float u[6], w2l[6][3];
    const unsigned* rowU = reinterpret_cast<const unsigned*>(Cb + (size_t)i * NF) + lane*3;
    {
        unsigned w0 = rowU[0], w1 = rowU[1], w2 = rowU[2];
        u[0] = bflo(w0) + b1[d0+0];
        u[1] = bfhi(w0) + b1[d0+1];
        u[2] = bflo(w1) + b1[d0+2];
        u[3] = bfhi(w1) + b1[d0+3];
        u[4] = bflo(w2) + b1[d0+4];
        u[5] = bfhi(w2) + b1[d0+5];
    }
    #pragma unroll
    for (int t = 0; t < 6; ++t)
        #pragma unroll
        for (int c = 0; c < 3; ++c) w2l[t][c] = W2[(d0 + t)*3 + c];

    int jreg = knn[i*KNN + (lane & 15)];

    float mx0 = -INFF, mx1 = -INFF, mx2 = -INFF;
    #pragma unroll
    for (int k = 0; k < KNN; ++k) {
        int j = __shfl(jreg, k);
        const unsigned* rowV = reinterpret_cast<const unsigned*>(Cb + (size_t)j * NF + TD) + lane*3;
        unsigned w0 = rowV[0], w1 = rowV[1], w2 = rowV[2];
        float v[6];
        v[0] = bflo(w0); v[1] = bfhi(w0);
        v[2] = bflo(w1); v[3] = bfhi(w1);
        v[4] = bflo(w2); v[5] = bfhi(w2);
        float s0 = 0.f, s1 = 0.f, s2 = 0.f;
        #pragma unroll
        for (int t = 0; t < 6; ++t) {
            float h = fmaxf(u[t] + v[t], 0.f);
            s0 = fmaf(h, w2l[t][0], s0);
            s1 = fmaf(h, w2l[t][1], s1);
            s2 = fmaf(h, w2l[t][2], s2);
        }
        #pragma unroll
        for (int o = 1; o < 64; o <<= 1) {
            s0 += __shfl_xor(s0, o);
            s1 += __shfl_xor(s1, o);
            s2 += __shfl_xor(s2, o);
        }
        mx0 = fmaxf(mx0, s0); mx1 = fmaxf(mx1, s1); mx2 = fmaxf(mx2, s2);
    }
    if (lane == 0) {
        out[i*3+0] = xyz[i*3+0] + mx0 + b2[0];
        out[i*3+1] = xyz[i*3+1] + mx1 + b2[1];
        out[i*3+2] = xyz[i*3+2] + mx2 + b2[2];
    }
}

// ---------------- launch ----------------

extern "C" void kernel_launch(void* const* d_in, const int* in_sizes, int n_in,
                              void* d_out, int out_size, void* d_ws, size_t ws_size,
                              hipStream_t stream) {
    const float* xyz  = (const float*)d_in[0];
    const float* feat = (const float*)d_in[1];
    const float* W1   = (const float*)d_in[2];
    const float* b1   = (const float*)d_in[3];
    const float* W2   = (const float*)d_in[4];
    const float* b2   = (const float*)d_in[5];
    float* out = (float*)d_out;

    char* ws = (char*)d_ws;
    int*            knn   = (int*)(ws + 0);                  //   524288 B
    float*          tiles = (float*)(ws + 524288);           //   131072 B
    __hip_bfloat16* Xb    = (__hip_bfloat16*)(ws + 655360);  //  6815744 B
    __hip_bfloat16* Wpt   = (__hip_bfloat16*)(ws + 7471104); //   638976 B
    __hip_bfloat16* Cb    = (__hip_bfloat16*)(ws + 8110080); // 12582912 B -> end 20692992

    prep_all   <<<dim3(N + NF),      dim3(256), 0, stream>>>(feat, xyz, W1, tiles, Xb, Wpt);
    knn_kernel <<<dim3(N/16),        dim3(256), 0, stream>>>(tiles, knn);
    gemm_kernel<<<dim3(N/64, NF/64), dim3(64),  0, stream>>>(Xb, Wpt, Cb);
    final_kernel<<<dim3(N/4),        dim3(256), 0, stream>>>(Cb, knn, xyz, b1, W2, b2, out);
}